// Round 5
// baseline (372.904 us; speedup 1.0000x reference)
//
#include <hip/hip_runtime.h>

// entmax-1.5 over rows of an 8192 x 4096 fp32 matrix, boolean mask (int32).
// One wave per row; 64 elems/lane as 32 packed fp16 pairs in regs.
// R4 post-mortem: VALU 21%, HBM 25%, occ 65% -- nothing saturated =>
// phase-serialized (load burst, then long Newton, then store). R5 shrinks the
// Newton phase ~5x via candidate prefiltering: tau* >= max-1, so only elems
// with z > mx-1 (~2 per lane on this data) matter. Each lane scatters its
// candidates into a conflict-free LDS slice ([wave][slot][lane] -> bank =
// lane%32), reads back 8 fp32 regs (-1e30 sentinels), and Newton sweeps only
// those. Rows where any lane overflows 8 slots (ballot) take the full-sweep
// fallback. Newton on convex decreasing g converges globally from any start.

typedef _Float16 h2 __attribute__((ext_vector_type(2)));

constexpr int NROWS = 8192;
constexpr int NCOL  = 4096;
constexpr int PAIRS = 32;   // packed fp16 pairs per lane (64 elems)
constexpr int CHUNK = 16;   // float4/int4 chunks per lane
constexpr int MAXIT = 12;   // Newton cap; early-exit typically ~5-6
constexpr int NC    = 8;    // candidate slots per lane

static __device__ __forceinline__ h2 pkrtz(float a, float b) {
    return __builtin_bit_cast(h2, __builtin_amdgcn_cvt_pkrtz(a, b));
}

static __device__ __forceinline__ float dot2acc(h2 a, h2 b, float c) {
#if __has_builtin(__builtin_amdgcn_fdot2)
    return __builtin_amdgcn_fdot2(a, b, c, false);   // v_dot2_f32_f16
#else
    return c + (float)a[0] * (float)b[0] + (float)a[1] * (float)b[1];
#endif
}

__global__ __launch_bounds__(256, 6)
void entmax15_kernel(const float* __restrict__ scores,
                     const int*   __restrict__ mask,
                     float*       __restrict__ out)
{
    // [wave][slot][lane]: lane-contiguous -> ds addr = lane*4 + slot*256 +
    // wave*2048 -> bank = lane%32, conflict-free for any divergent slot index.
    __shared__ float cand[4][NC][64];

    const int lane = threadIdx.x & 63;
    const int wave = threadIdx.x >> 6;          // 4 waves per block = 4 rows
    const int row  = (blockIdx.x << 2) | wave;  // grid = 2048 -> rows 0..8191

    const float* srow = scores + (size_t)row * NCOL;
    const int*   mrow = mask   + (size_t)row * NCOL;
    float*       orow = out    + (size_t)row * NCOL;

    h2 y[PAIRS];
    float mx = -1e30f;

    // Coalesced float4/int4 loads; pack to fp16 pairs, track fp32 row max.
    #pragma unroll
    for (int c = 0; c < CHUNK; ++c) {
        const int base = c * 256 + lane * 4;
        const float4 s4 = *reinterpret_cast<const float4*>(srow + base);
        const int4   m4 = *reinterpret_cast<const int4*>(mrow + base);
        const float z0 = m4.x ? s4.x * 0.5f : -5000.0f;  // where(mask, s/2, -5000)
        const float z1 = m4.y ? s4.y * 0.5f : -5000.0f;
        const float z2 = m4.z ? s4.z * 0.5f : -5000.0f;
        const float z3 = m4.w ? s4.w * 0.5f : -5000.0f;
        mx = fmaxf(mx, fmaxf(fmaxf(z0, z1), fmaxf(z2, z3)));
        y[c * 2 + 0] = pkrtz(z0, z1);
        y[c * 2 + 1] = pkrtz(z2, z3);
    }

    // Row max across the wave (butterfly; result uniform in all lanes).
    #pragma unroll
    for (int off = 1; off < 64; off <<= 1)
        mx = fmaxf(mx, __shfl_xor(mx, off, 64));

    const float thresh = mx - 1.0f;   // tau* >= thresh: elems <= thresh are dead

    // Pre-fill candidate slots with sentinels, then scatter over-threshold
    // values (dynamic slot index must go through LDS, not registers).
    #pragma unroll
    for (int j = 0; j < NC; ++j) cand[wave][j][lane] = -1e30f;

    int k = 0;
    #pragma unroll
    for (int p = 0; p < PAIRS; ++p) {
        const float v0 = (float)y[p][0];
        const float v1 = (float)y[p][1];
        if (v0 > thresh) { cand[wave][k > NC - 1 ? NC - 1 : k][lane] = v0; ++k; }
        if (v1 > thresh) { cand[wave][k > NC - 1 ? NC - 1 : k][lane] = v1; ++k; }
    }

    float t = thresh;   // start left of root: g(thresh) >= 0

    if (__ballot(k > NC) == 0ull) {
        // Fast path: every lane's candidates fit. Sweep 8 fp32 slots.
        const float c0 = cand[wave][0][lane], c1 = cand[wave][1][lane];
        const float c2 = cand[wave][2][lane], c3 = cand[wave][3][lane];
        const float c4 = cand[wave][4][lane], c5 = cand[wave][5][lane];
        const float c6 = cand[wave][6][lane], c7 = cand[wave][7][lane];
        #pragma unroll 1
        for (int it = 0; it < MAXIT; ++it) {
            float s2a = 0.f, s2b = 0.f, s1a = 0.f, s1b = 0.f;
            float d;
            d = fmaxf(c0 - t, 0.f); s2a = fmaf(d, d, s2a); s1a += d;
            d = fmaxf(c1 - t, 0.f); s2b = fmaf(d, d, s2b); s1b += d;
            d = fmaxf(c2 - t, 0.f); s2a = fmaf(d, d, s2a); s1a += d;
            d = fmaxf(c3 - t, 0.f); s2b = fmaf(d, d, s2b); s1b += d;
            d = fmaxf(c4 - t, 0.f); s2a = fmaf(d, d, s2a); s1a += d;
            d = fmaxf(c5 - t, 0.f); s2b = fmaf(d, d, s2b); s1b += d;
            d = fmaxf(c6 - t, 0.f); s2a = fmaf(d, d, s2a); s1a += d;
            d = fmaxf(c7 - t, 0.f); s2b = fmaf(d, d, s2b); s1b += d;
            float s2 = s2a + s2b;
            float s1 = s1a + s1b;
            #pragma unroll
            for (int off = 1; off < 64; off <<= 1) {
                s2 += __shfl_xor(s2, off, 64);
                s1 += __shfl_xor(s1, off, 64);
            }
            const float step = (s2 - 1.0f) / (2.0f * s1);
            t += step;
            if (__builtin_fabsf(step) < 1e-4f) break;  // wave-uniform
        }
    } else {
        // Fallback (~1-2% of rows): full packed-fp16 sweep (R4 path).
        #pragma unroll 1
        for (int it = 0; it < MAXIT; ++it) {
            const _Float16 th = (_Float16)t;
            const h2 t2   = {th, th};
            const h2 zero = {(_Float16)0.f, (_Float16)0.f};
            const h2 one2 = {(_Float16)1.f, (_Float16)1.f};
            float s2a = 0.f, s2b = 0.f, s1a = 0.f, s1b = 0.f;
            #pragma unroll
            for (int i = 0; i < PAIRS; i += 2) {
                const h2 d0 = __builtin_elementwise_max(y[i]     - t2, zero);
                const h2 d1 = __builtin_elementwise_max(y[i + 1] - t2, zero);
                s2a = dot2acc(d0, d0, s2a);
                s1a = dot2acc(d0, one2, s1a);
                s2b = dot2acc(d1, d1, s2b);
                s1b = dot2acc(d1, one2, s1b);
            }
            float s2 = s2a + s2b;
            float s1 = s1a + s1b;
            #pragma unroll
            for (int off = 1; off < 64; off <<= 1) {
                s2 += __shfl_xor(s2, off, 64);
                s1 += __shfl_xor(s1, off, 64);
            }
            const float step = (s2 - 1.0f) / (2.0f * s1);
            t += step;
            if (__builtin_fabsf(step) < 1e-4f) break;
        }
    }

    // Epilogue in fp32: p = relu(z - tau)^2, coalesced float4 stores.
    #pragma unroll
    for (int c = 0; c < CHUNK; ++c) {
        const int base = c * 256 + lane * 4;
        const float v0 = (float)y[c * 2 + 0][0];
        const float v1 = (float)y[c * 2 + 0][1];
        const float v2 = (float)y[c * 2 + 1][0];
        const float v3 = (float)y[c * 2 + 1][1];
        float4 o;
        float d;
        d = fmaxf(v0 - t, 0.f); o.x = d * d;
        d = fmaxf(v1 - t, 0.f); o.y = d * d;
        d = fmaxf(v2 - t, 0.f); o.z = d * d;
        d = fmaxf(v3 - t, 0.f); o.w = d * d;
        *reinterpret_cast<float4*>(orow + base) = o;
    }
}

extern "C" void kernel_launch(void* const* d_in, const int* in_sizes, int n_in,
                              void* d_out, int out_size, void* d_ws, size_t ws_size,
                              hipStream_t stream)
{
    const float* scores = (const float*)d_in[0];
    const int*   mask   = (const int*)d_in[1];
    float*       out    = (float*)d_out;

    dim3 grid(NROWS / 4);   // 4 rows (waves) per 256-thread block
    dim3 block(256);
    hipLaunchKernelGGL(entmax15_kernel, grid, block, 0, stream,
                       scores, mask, out);
}

// Round 6
// 310.317 us; speedup vs baseline: 1.2017x; 1.2017x over previous
//
#include <hip/hip_runtime.h>

// entmax-1.5 over rows of an 8192 x 4096 fp32 matrix, boolean mask (int32).
// R6: one 256-thread BLOCK per row, 16 fp32 elems per lane. Rationale
// (R1-R5 post-mortems): 64 elems/lane in a wave-per-row layout always loses
// -- AGPR shuffling (R1/R2/R4), scratch spill (R5: WRITE_SIZE 131->265 MB),
// or 2 waves/SIMD occupancy (R2). 16 fp32 regs of state -> ~60 VGPRs total,
// 8 waves/SIMD, all 8 loads in flight, full fp32 precision.
// tau* solves g(tau) = sum(relu(z-tau)^2) - 1 = 0; g convex decreasing,
// |g'| >= 2 at the root -> Newton from tau0 = max-1 converges monotonically.
// Per-iteration reduction: 6-step wave butterfly + 4-partial LDS combine.

constexpr int NROWS = 8192;
constexpr int NCOL  = 4096;
constexpr int EPT   = 16;   // elements per thread (4096 / 256)
constexpr int NLD   = 4;    // float4/int4 loads per thread
constexpr int MAXIT = 10;   // Newton cap; uniform early-exit typically ~6

__global__ __launch_bounds__(256, 8)
void entmax15_kernel(const float* __restrict__ scores,
                     const int*   __restrict__ mask,
                     float*       __restrict__ out)
{
    __shared__ float redA[4], redB[4];

    const int tid  = threadIdx.x;
    const int lane = tid & 63;
    const int wave = tid >> 6;
    const int row  = blockIdx.x;

    const float* srow = scores + (size_t)row * NCOL;
    const int*   mrow = mask   + (size_t)row * NCOL;
    float*       orow = out    + (size_t)row * NCOL;

    float z[EPT];

    // Coalesced: sweep c covers columns [c*1024, c*1024+1024), thread takes
    // 4 consecutive floats at c*1024 + tid*4 (16B aligned). 8 independent
    // loads -- all can be in flight.
    #pragma unroll
    for (int c = 0; c < NLD; ++c) {
        const int base = c * 1024 + tid * 4;
        const float4 s4 = *reinterpret_cast<const float4*>(srow + base);
        const int4   m4 = *reinterpret_cast<const int4*>(mrow + base);
        z[c * 4 + 0] = m4.x ? s4.x * 0.5f : -5000.0f;  // where(mask, s/2, -5000)
        z[c * 4 + 1] = m4.y ? s4.y * 0.5f : -5000.0f;
        z[c * 4 + 2] = m4.z ? s4.z * 0.5f : -5000.0f;
        z[c * 4 + 3] = m4.w ? s4.w * 0.5f : -5000.0f;
    }

    // Row max: per-lane tree, wave butterfly, 4-wave LDS combine.
    float mx = z[0];
    #pragma unroll
    for (int i = 1; i < EPT; ++i) mx = fmaxf(mx, z[i]);
    #pragma unroll
    for (int off = 1; off < 64; off <<= 1)
        mx = fmaxf(mx, __shfl_xor(mx, off, 64));
    if (lane == 0) redA[wave] = mx;
    __syncthreads();
    mx = fmaxf(fmaxf(redA[0], redA[1]), fmaxf(redA[2], redA[3]));

    // Newton from the left bracket: g(mx-1) >= 0 (max elem contributes 1);
    // near the root s1 = sum relu(z-t) >= 1, so no divide-by-~0.
    float t = mx - 1.0f;
    #pragma unroll 1
    for (int it = 0; it < MAXIT; ++it) {
        __syncthreads();   // protect redA/redB from previous iteration's reads
        float s2a = 0.f, s2b = 0.f, s1a = 0.f, s1b = 0.f;
        #pragma unroll
        for (int i = 0; i < EPT; i += 2) {
            const float d0 = fmaxf(z[i + 0] - t, 0.f);
            const float d1 = fmaxf(z[i + 1] - t, 0.f);
            s2a = fmaf(d0, d0, s2a);  s1a += d0;
            s2b = fmaf(d1, d1, s2b);  s1b += d1;
        }
        float s2 = s2a + s2b;
        float s1 = s1a + s1b;
        #pragma unroll
        for (int off = 1; off < 64; off <<= 1) {
            s2 += __shfl_xor(s2, off, 64);
            s1 += __shfl_xor(s1, off, 64);
        }
        if (lane == 0) { redA[wave] = s1; redB[wave] = s2; }
        __syncthreads();
        s1 = (redA[0] + redA[1]) + (redA[2] + redA[3]);
        s2 = (redB[0] + redB[1]) + (redB[2] + redB[3]);
        const float step = (s2 - 1.0f) / (2.0f * s1);
        t += step;                                  // identical in all threads
        if (__builtin_fabsf(step) < 1e-5f) break;   // block-uniform break
    }

    // Epilogue: p = relu(z - tau)^2, coalesced float4 stores.
    #pragma unroll
    for (int c = 0; c < NLD; ++c) {
        const int base = c * 1024 + tid * 4;
        float4 o;
        float d;
        d = fmaxf(z[c * 4 + 0] - t, 0.f); o.x = d * d;
        d = fmaxf(z[c * 4 + 1] - t, 0.f); o.y = d * d;
        d = fmaxf(z[c * 4 + 2] - t, 0.f); o.z = d * d;
        d = fmaxf(z[c * 4 + 3] - t, 0.f); o.w = d * d;
        *reinterpret_cast<float4*>(orow + base) = o;
    }
}

extern "C" void kernel_launch(void* const* d_in, const int* in_sizes, int n_in,
                              void* d_out, int out_size, void* d_ws, size_t ws_size,
                              hipStream_t stream)
{
    const float* scores = (const float*)d_in[0];
    const int*   mask   = (const int*)d_in[1];
    float*       out    = (float*)d_out;

    dim3 grid(NROWS);    // one 256-thread block per row
    dim3 block(256);
    hipLaunchKernelGGL(entmax15_kernel, grid, block, 0, stream,
                       scores, mask, out);
}